// Round 4
// baseline (2059.840 us; speedup 1.0000x reference)
//
#include <hip/hip_runtime.h>
#include <hip/hip_bf16.h>

// GraphUnet forward.
//  - Down path (feeds both top-k pools) in float64 via f64 MFMA
//    (v_mfma_f64_16x16x4): rank-exact ordering vs f64 numpy ref.
//  - top_k = bitonic sort on (f64 score bits, index), jax tie-break.
//  - Up path + pool_out: bf16 MFMA (16x16x32), fp32 accumulate (harness
//    compares in bf16; we sit at ~1.5 ulp of the output scale).
//  - A1 = A[idx][:,idx] never materialized: A1@Y = gather_idx(A @ scatter_idx(Y)).
//  - R4: single-barrier double-buffered K-loops (reg prefetch -> LDS[1-buf])
//    in both MFMA kernels to hide global-load latency at low occupancy.

constexpr int NN  = 4096;
constexpr int DIM = 320;
constexpr int KP0 = 3686;
constexpr int KP1 = 2580;

typedef __attribute__((ext_vector_type(8))) short short8_t;
typedef __attribute__((ext_vector_type(4))) float floatx4;
typedef __attribute__((ext_vector_type(4))) double double4v;

// ---------------- f64 MFMA GEMM: C = A @ B (+bias, relu) ---------------------
// A: M x K (f32/f64) row-major.  B: K x N (f32/f64) row-major, staged as f64.
// C: M x N f64.  Tiles 64x32, BK=32; 4 waves (2x2), wave = 32m x 16n.
// Double-buffered LDS, one barrier per K-iter.
template<typename TA, typename TB, int EPI, bool AGATHER>
__global__ __launch_bounds__(256) void dmfma_k(
    const TA* __restrict__ Ag, const TB* __restrict__ Bg, double* __restrict__ Cg,
    const float* __restrict__ bias, const int* __restrict__ aidx,
    int M, int N, int K, int lda, int ldb, int ldc)
{
  constexpr int BM = 64, BN = 32, BK = 32;
  constexpr int SA = (sizeof(TA) == 4) ? 36 : 34;   // row stride, elements
  constexpr int SB = 34;
  constexpr int EC  = 16 / (int)sizeof(TA);         // A elems per 16B chunk
  constexpr int CPR = BK / EC;                      // A chunks per row
  constexpr int ACH = (BM * CPR) / 256;             // A chunks per thread
  __shared__ TA     As[2][BM][SA];
  __shared__ double Bs[2][BK][SB];
  const int tid = threadIdx.x;
  const int wave = tid >> 6, lane = tid & 63;
  const int wm = wave >> 1, wn = wave & 1;
  const int m0 = blockIdx.y * BM, n0 = blockIdx.x * BN;
  const int ml = lane & 15, kl = lane >> 4;

  // precompute staging coordinates (rows resolved once, incl. gather+clamp)
  int    a_r[ACH], a_c[ACH];
  size_t a_off[ACH];
#pragma unroll
  for (int i = 0; i < ACH; ++i) {
    int ch = tid + i * 256;
    a_r[i] = ch / CPR; a_c[i] = (ch % CPR) * EC;
    int row = m0 + a_r[i]; if (row >= M) row = M - 1;
    int ar = AGATHER ? aidx[row] : row;
    a_off[i] = (size_t)ar * lda + a_c[i];
  }
  int    b_r[2], b_c[2];
#pragma unroll
  for (int i = 0; i < 2; ++i) {
    int ch = tid + i * 256;
    b_r[i] = ch >> 4; b_c[i] = (ch & 15) * 2;
  }

  uint4 aReg[ACH];
  TB    bReg[2][2];
  auto loadTiles = [&](int k0) {
#pragma unroll
    for (int i = 0; i < ACH; ++i)
      aReg[i] = *(const uint4*)&Ag[a_off[i] + k0];
#pragma unroll
    for (int i = 0; i < 2; ++i) {
      const TB* bp = Bg + (size_t)(k0 + b_r[i]) * ldb + n0 + b_c[i];
      bReg[i][0] = bp[0]; bReg[i][1] = bp[1];
    }
  };
  auto storeTiles = [&](int buf) {
#pragma unroll
    for (int i = 0; i < ACH; ++i)
      *(uint4*)&As[buf][a_r[i]][a_c[i]] = aReg[i];
#pragma unroll
    for (int i = 0; i < 2; ++i) {
      Bs[buf][b_r[i]][b_c[i]]     = (double)bReg[i][0];
      Bs[buf][b_r[i]][b_c[i] + 1] = (double)bReg[i][1];
    }
  };

  double4v acc[2];
#pragma unroll
  for (int i = 0; i < 2; ++i)
#pragma unroll
    for (int r = 0; r < 4; ++r) acc[i][r] = 0.0;

  loadTiles(0);
  storeTiles(0);
  __syncthreads();
  int buf = 0;
  for (int k0 = 0; k0 < K; k0 += BK) {
    const bool has_next = (k0 + BK < K);
    if (has_next) loadTiles(k0 + BK);
#pragma unroll
    for (int ks = 0; ks < BK; ks += 4) {
      double b  = Bs[buf][ks + kl][wn * 16 + ml];
      double a0 = (double)As[buf][wm * 32 + ml][ks + kl];
      double a1 = (double)As[buf][wm * 32 + 16 + ml][ks + kl];
      acc[0] = __builtin_amdgcn_mfma_f64_16x16x4f64(a0, b, acc[0], 0, 0, 0);
      acc[1] = __builtin_amdgcn_mfma_f64_16x16x4f64(a1, b, acc[1], 0, 0, 0);
    }
    if (has_next) {
      storeTiles(buf ^ 1);      // other buffer: safe while others compute(k0)
      __syncthreads();          // writes visible before compute(k0+BK)
      buf ^= 1;
    }
  }
  const int n = n0 + wn * 16 + ml;
#pragma unroll
  for (int mi = 0; mi < 2; ++mi)
#pragma unroll
    for (int r = 0; r < 4; ++r) {
      int m = m0 + wm * 32 + mi * 16 + kl * 4 + r;
      if (m >= M || n >= N) continue;
      double v = acc[mi][r];
      if (EPI == 1) { v += (double)bias[n]; v = v > 0.0 ? v : 0.0; }
      Cg[(size_t)m * ldc + n] = v;
    }
}

// ---------------- bf16 MFMA GEMM: C = A @ Bt^T (+bias,relu)(+residual) -------
// A:  M x K row-major bf16 (rows optionally gathered via aidx).
// Bt: N x K row-major bf16.  C: M x N (f32 or bf16 per OUTBF).
// Tiles 128x64, BK=64, 4 waves (2x2), each wave 64x32.  Double-buffered LDS.
template<int EPI, bool AGATHER, bool OUTBF>
__global__ __launch_bounds__(256) void mfma_gemm_k(
    const __hip_bfloat16* __restrict__ Ag, const __hip_bfloat16* __restrict__ Btg,
    void* __restrict__ Cgv, const float* __restrict__ bias,
    const float* __restrict__ Rg, const int* __restrict__ aidx,
    int M, int N, int K, int lda, int ldb, int ldc, int ldr)
{
  constexpr int BM = 128, BN = 64, BK = 64, BKP = 72;
  __shared__ ushort As[2][BM][BKP];
  __shared__ ushort Bs[2][BN][BKP];
  const int tid  = threadIdx.x;
  const int wave = tid >> 6, lane = tid & 63;
  const int wm = wave >> 1, wn = wave & 1;
  const int m0 = blockIdx.y * BM, n0 = blockIdx.x * BN;
  const int mlane = lane & 15;
  const int kq    = (lane >> 4) * 8;

  int    a_r[4], a_c[4];
  size_t a_off[4];
#pragma unroll
  for (int i = 0; i < 4; ++i) {
    int ch = tid + i * 256;
    a_r[i] = ch >> 3; a_c[i] = (ch & 7) * 8;
    int row = m0 + a_r[i]; if (row >= M) row = M - 1;
    int ar = AGATHER ? aidx[row] : row;
    a_off[i] = (size_t)ar * lda + a_c[i];
  }
  int    b_r[2], b_c[2];
  size_t b_off[2];
#pragma unroll
  for (int i = 0; i < 2; ++i) {
    int ch = tid + i * 256;
    b_r[i] = ch >> 3; b_c[i] = (ch & 7) * 8;
    int row = n0 + b_r[i]; if (row >= N) row = N - 1;
    b_off[i] = (size_t)row * ldb + b_c[i];
  }

  uint4 aReg[4], bReg[2];
  auto loadTiles = [&](int k0) {
#pragma unroll
    for (int i = 0; i < 4; ++i)
      aReg[i] = *(const uint4*)((const ushort*)Ag + a_off[i] + k0);
#pragma unroll
    for (int i = 0; i < 2; ++i)
      bReg[i] = *(const uint4*)((const ushort*)Btg + b_off[i] + k0);
  };
  auto storeTiles = [&](int buf) {
#pragma unroll
    for (int i = 0; i < 4; ++i) *(uint4*)&As[buf][a_r[i]][a_c[i]] = aReg[i];
#pragma unroll
    for (int i = 0; i < 2; ++i) *(uint4*)&Bs[buf][b_r[i]][b_c[i]] = bReg[i];
  };

  floatx4 acc[4][2];
#pragma unroll
  for (int i = 0; i < 4; ++i)
#pragma unroll
    for (int j = 0; j < 2; ++j) acc[i][j] = (floatx4)0.f;

  loadTiles(0);
  storeTiles(0);
  __syncthreads();
  int buf = 0;
  for (int k0 = 0; k0 < K; k0 += BK) {
    const bool has_next = (k0 + BK < K);
    if (has_next) loadTiles(k0 + BK);
#pragma unroll
    for (int ks = 0; ks < BK; ks += 32) {
      short8_t aF[4], bF[2];
#pragma unroll
      for (int mi = 0; mi < 4; ++mi)
        aF[mi] = *(const short8_t*)&As[buf][wm * 64 + mi * 16 + mlane][ks + kq];
#pragma unroll
      for (int ni = 0; ni < 2; ++ni)
        bF[ni] = *(const short8_t*)&Bs[buf][wn * 32 + ni * 16 + mlane][ks + kq];
#pragma unroll
      for (int mi = 0; mi < 4; ++mi)
#pragma unroll
        for (int ni = 0; ni < 2; ++ni)
          acc[mi][ni] = __builtin_amdgcn_mfma_f32_16x16x32_bf16(
              aF[mi], bF[ni], acc[mi][ni], 0, 0, 0);
    }
    if (has_next) {
      storeTiles(buf ^ 1);
      __syncthreads();
      buf ^= 1;
    }
  }
  const int crow = (lane >> 4) * 4;
#pragma unroll
  for (int mi = 0; mi < 4; ++mi)
#pragma unroll
    for (int ni = 0; ni < 2; ++ni) {
      int n = n0 + wn * 32 + ni * 16 + mlane;
      if (n >= N) continue;
#pragma unroll
      for (int r = 0; r < 4; ++r) {
        int m = m0 + wm * 64 + mi * 16 + crow + r;
        if (m >= M) continue;
        float v = acc[mi][ni][r];
        if (EPI >= 1) { v += bias[n]; v = v > 0.f ? v : 0.f; }
        if (EPI == 2) v += Rg[(size_t)m * ldr + n];
        if (OUTBF) ((__hip_bfloat16*)Cgv)[(size_t)m * ldc + n] = __float2bfloat16(v);
        else       ((float*)Cgv)[(size_t)m * ldc + n] = v;
      }
    }
}

// ---------------- conversions ------------------------------------------------
__global__ __launch_bounds__(256) void cvtA_bf16_k(
    const float* __restrict__ src, __hip_bfloat16* __restrict__ dst, int n)
{
  int g = (blockIdx.x * 256 + threadIdx.x) * 4;
  if (g + 3 < n) {
    float4 v = *(const float4*)(src + g);
    dst[g]     = __float2bfloat16(v.x);
    dst[g + 1] = __float2bfloat16(v.y);
    dst[g + 2] = __float2bfloat16(v.z);
    dst[g + 3] = __float2bfloat16(v.w);
  } else {
    for (int i = g; i < n; ++i) dst[i] = __float2bfloat16(src[i]);
  }
}

// f32 src[R][C] -> bf16 dst[C][R], 64x64 LDS tiles, conflict-free (+1 pad)
__global__ __launch_bounds__(256) void transpose_bf16_k(
    const float* __restrict__ src, __hip_bfloat16* __restrict__ dst, int R, int C)
{
  __shared__ float s[64][65];
  int r0 = blockIdx.y * 64, c0 = blockIdx.x * 64;
  int tid = threadIdx.x;
  int c = tid & 63, rr = tid >> 6;
  for (int i = 0; i < 64; i += 4) {
    int r = rr + i;
    s[r][c] = (r0 + r < R && c0 + c < C) ? src[(size_t)(r0 + r) * C + c0 + c] : 0.f;
  }
  __syncthreads();
  int r2 = tid & 63, cc = tid >> 6;
  for (int i = 0; i < 64; i += 4) {
    int c2 = cc + i;
    if (c0 + c2 < C && r0 + r2 < R)
      dst[(size_t)(c0 + c2) * R + r0 + r2] = __float2bfloat16(s[r2][c2]);
  }
}

// ---------------- pooling scores -> sort keys --------------------------------
__global__ __launch_bounds__(64) void score_keys_k(
    const double* __restrict__ Xd, const float* __restrict__ pw,
    const float* __restrict__ pb, int n, ulonglong2* __restrict__ keys)
{
  int i = blockIdx.x;
  int lane = threadIdx.x;
  if (i >= n) {
    if (lane == 0) { ulonglong2 kv; kv.x = 0ull; kv.y = 0xFFFFFFFFull; keys[i] = kv; }
    return;
  }
  double p = 0.0;
#pragma unroll
  for (int c = 0; c < DIM; c += 64)
    p += Xd[(size_t)i * DIM + c + lane] * (double)pw[c + lane];
  for (int o = 32; o > 0; o >>= 1) p += __shfl_down(p, o, 64);
  if (lane == 0) {
    double z = (p + (double)pb[0]) / 100.0;
    double s;
    if (z >= 0.0) s = 1.0 / (1.0 + exp(-z));
    else { double e = exp(z); s = e / (1.0 + e); }   // stable branch (jax/scipy)
    ulonglong2 kv;
    kv.x = (unsigned long long)__double_as_longlong(s);
    kv.y = (unsigned long long)i;
    keys[i] = kv;
  }
}

__device__ __forceinline__ bool key_gt(const ulonglong2 a, const ulonglong2 b) {
  return (a.x > b.x) || (a.x == b.x && a.y < b.y);
}

__global__ __launch_bounds__(1024) void bitonic_k(
    const ulonglong2* __restrict__ keys, int k_keep,
    int* __restrict__ idx, double* __restrict__ vals)
{
  extern __shared__ ulonglong2 s[];
  int tid = threadIdx.x;
  for (int i = tid; i < NN; i += 1024) s[i] = keys[i];
  __syncthreads();
  for (int k = 2; k <= NN; k <<= 1) {
    for (int j = k >> 1; j > 0; j >>= 1) {
      for (int t = tid; t < NN; t += 1024) {
        int p = t ^ j;
        if (p > t) {
          ulonglong2 a = s[t], b = s[p];
          bool desc = ((t & k) == 0);
          bool sw = desc ? key_gt(b, a) : key_gt(a, b);
          if (sw) { s[t] = b; s[p] = a; }
        }
      }
      __syncthreads();
    }
  }
  for (int r = tid; r < k_keep; r += 1024) {
    idx[r]  = (int)s[r].y;
    vals[r] = __longlong_as_double((long long)s[r].x);
  }
}

// ---------------- small helpers ----------------------------------------------
__global__ void scatter64_k(const double* __restrict__ src, const int* __restrict__ sel,
                            const double* __restrict__ vals, const int* __restrict__ scat,
                            double* __restrict__ dst, __hip_bfloat16* __restrict__ comp,
                            int kcnt)
{
  int g = blockIdx.x * 256 + threadIdx.x;
  if (g >= kcnt * DIM) return;
  int r = g / DIM, c = g % DIM;
  double v = src[(size_t)sel[r] * DIM + c] * vals[r];
  dst[(size_t)scat[r] * DIM + c] = v;
  comp[g] = __float2bfloat16((float)v);
}

__global__ void scatter32_from64_k(const double* __restrict__ src, const int* __restrict__ sel,
                                   const double* __restrict__ vals, const int* __restrict__ scat,
                                   float* __restrict__ dst, int kcnt)
{
  int g = blockIdx.x * 256 + threadIdx.x;
  if (g >= kcnt * DIM) return;
  int r = g / DIM, c = g % DIM;
  dst[(size_t)scat[r] * DIM + c] = (float)(src[(size_t)sel[r] * DIM + c] * vals[r]);
}

__global__ void scatter32_k(const float* __restrict__ src, const int* __restrict__ scat,
                            float* __restrict__ dst, int kcnt)
{
  int g = blockIdx.x * 256 + threadIdx.x;
  if (g >= kcnt * DIM) return;
  int r = g / DIM, c = g % DIM;
  dst[(size_t)scat[r] * DIM + c] = src[g];
}

__global__ void cvt64to32_k(const double* __restrict__ src, float* __restrict__ dst, int n)
{
  int g = blockIdx.x * 256 + threadIdx.x;
  if (g < n) dst[g] = (float)src[g];
}

__global__ void compose_k(const int* __restrict__ idx0, const int* __restrict__ idx1,
                          int* __restrict__ idx01, int n)
{
  int g = blockIdx.x * 256 + threadIdx.x;
  if (g < n) idx01[g] = idx0[idx1[g]];
}

__global__ void copycols_k(float* __restrict__ xcat, const float* __restrict__ x0)
{
  int g = blockIdx.x * 256 + threadIdx.x;
  if (g >= NN * DIM) return;
  int r = g / DIM, c = g % DIM;
  xcat[(size_t)r * (2 * DIM) + DIM + c] = x0[g];
}

__global__ void diag_k(float* __restrict__ po)
{
  int g = blockIdx.x * 256 + threadIdx.x;
  if (g < KP0) po[(size_t)g * KP0 + g] = 1.0f;
}

// ---------------- launch ------------------------------------------------------
extern "C" void kernel_launch(void* const* d_in, const int* in_sizes, int n_in,
                              void* d_out, int out_size, void* d_ws, size_t ws_size,
                              hipStream_t stream) {
  const float* A        = (const float*)d_in[0];
  const float* X        = (const float*)d_in[1];
  const float* w_start  = (const float*)d_in[2];
  const float* b_start  = (const float*)d_in[3];
  const float* w_down0  = (const float*)d_in[4];
  const float* b_down0  = (const float*)d_in[5];
  const float* w_down1  = (const float*)d_in[6];
  const float* b_down1  = (const float*)d_in[7];
  const float* p_w0     = (const float*)d_in[8];
  const float* p_b0     = (const float*)d_in[9];
  const float* p_w1     = (const float*)d_in[10];
  const float* p_b1     = (const float*)d_in[11];
  const float* w_bottom = (const float*)d_in[12];
  const float* b_bottom = (const float*)d_in[13];
  const float* w_up0    = (const float*)d_in[14];
  const float* b_up0    = (const float*)d_in[15];
  const float* w_up1    = (const float*)d_in[16];
  const float* b_up1    = (const float*)d_in[17];
  const float* w_end    = (const float*)d_in[18];
  const float* b_end    = (const float*)d_in[19];

  float* out_x  = (float*)d_out;             // Xout   [4096,320]
  float* out_x0 = out_x + NN * DIM;          // X0     [4096,320]
  float* out_po = out_x0 + NN * DIM;         // pool   [3686,3686]

  char*  wsb = (char*)d_ws;
  size_t off = 0;
  auto alloc = [&](size_t bytes) -> void* {
    void* p = wsb + off; off = (off + bytes + 255) & ~(size_t)255; return p;
  };
  double* B1   = (double*)alloc((size_t)NN * DIM * 8);
  double* B2   = (double*)alloc((size_t)NN * DIM * 8);
  double* B3   = (double*)alloc((size_t)NN * DIM * 8);
  float*  Xd0f = (float*) alloc((size_t)NN * DIM * 4);
  float*  Xd1f = (float*) alloc((size_t)KP0 * DIM * 4);
  float*  Xs32 = (float*) alloc((size_t)NN * DIM * 4);
  float*  Xc   = (float*) alloc((size_t)KP0 * DIM * 4);
  float*  Xcat = (float*) alloc((size_t)NN * 2 * DIM * 4);
  __hip_bfloat16* Abf  = (__hip_bfloat16*)alloc((size_t)NN * NN * 2);
  __hip_bfloat16* XbfT = (__hip_bfloat16*)alloc((size_t)2 * DIM * NN * 2);
  __hip_bfloat16* Tbf  = (__hip_bfloat16*)alloc((size_t)NN * 2 * DIM * 2);
  __hip_bfloat16* Pbf  = (__hip_bfloat16*)alloc((size_t)KP0 * DIM * 2);
  __hip_bfloat16* wbT  = (__hip_bfloat16*)alloc((size_t)DIM * DIM * 2);
  __hip_bfloat16* wu0T = (__hip_bfloat16*)alloc((size_t)DIM * DIM * 2);
  __hip_bfloat16* wu1T = (__hip_bfloat16*)alloc((size_t)DIM * DIM * 2);
  __hip_bfloat16* weT  = (__hip_bfloat16*)alloc((size_t)DIM * 2 * DIM * 2);
  ulonglong2* keys = (ulonglong2*)alloc((size_t)NN * 16);
  int*    idx0  = (int*)   alloc(4096 * 4);
  double* vals0 = (double*)alloc(4096 * 8);
  int*    idx1  = (int*)   alloc(4096 * 4);
  double* vals1 = (double*)alloc(4096 * 8);
  int*    idx01 = (int*)   alloc(4096 * 4);

  const dim3 blk(256);
  auto cdiv = [](int a, int b) { return (a + b - 1) / b; };
  const dim3 gd_big(DIM / 32, NN / 64);      // dmfma: M=4096, N=320 -> 640 blocks
  const dim3 gd_k0 (DIM / 32, cdiv(KP0, 64));

  // One-time conversions (independent of everything downstream)
  cvtA_bf16_k<<<cdiv(NN * NN / 4, 256), blk, 0, stream>>>(A, Abf, NN * NN);
  transpose_bf16_k<<<dim3(5, 5),  blk, 0, stream>>>(w_bottom, wbT,  DIM, DIM);
  transpose_bf16_k<<<dim3(5, 5),  blk, 0, stream>>>(w_up0,    wu0T, DIM, DIM);
  transpose_bf16_k<<<dim3(5, 5),  blk, 0, stream>>>(w_up1,    wu1T, DIM, DIM);
  transpose_bf16_k<<<dim3(5, 10), blk, 0, stream>>>(w_end,    weT,  2 * DIM, DIM);

  // ---- down path, f64 MFMA ----
  // 1) T = A @ X
  dmfma_k<float, float, 0, false><<<gd_big, blk, 0, stream>>>(
      A, X, B1, nullptr, nullptr, NN, DIM, NN, NN, DIM, DIM);
  // 2) X0 = relu(T @ w_start + b)
  dmfma_k<double, float, 1, false><<<gd_big, blk, 0, stream>>>(
      B1, w_start, B2, b_start, nullptr, NN, DIM, DIM, DIM, DIM, DIM);
  cvt64to32_k<<<cdiv(NN * DIM, 256), blk, 0, stream>>>(B2, out_x0, NN * DIM);
  // 3) T = A @ X0
  dmfma_k<float, double, 0, false><<<gd_big, blk, 0, stream>>>(
      A, B2, B1, nullptr, nullptr, NN, DIM, NN, NN, DIM, DIM);
  // 4) Xd0 = relu(T @ w_down0 + b)
  dmfma_k<double, float, 1, false><<<gd_big, blk, 0, stream>>>(
      B1, w_down0, B3, b_down0, nullptr, NN, DIM, DIM, DIM, DIM, DIM);
  cvt64to32_k<<<cdiv(NN * DIM, 256), blk, 0, stream>>>(B3, Xd0f, NN * DIM);
  // 5) pool0 scores -> sort -> idx0, vals0
  score_keys_k<<<NN, dim3(64), 0, stream>>>(B3, p_w0, p_b0, NN, keys);
  bitonic_k<<<1, dim3(1024), 65536, stream>>>(keys, KP0, idx0, vals0);
  // 6) Xp0: scattered f64 + compact bf16 (for pool_out)
  hipMemsetAsync(B2, 0, (size_t)NN * DIM * 8, stream);
  scatter64_k<<<cdiv(KP0 * DIM, 256), blk, 0, stream>>>(B3, idx0, vals0, idx0, B2, Pbf, KP0);
  // 7) T = A @ Xp0s ; Xd1 = relu(gather_idx0(T) @ w_down1 + b)
  dmfma_k<float, double, 0, false><<<gd_big, blk, 0, stream>>>(
      A, B2, B1, nullptr, nullptr, NN, DIM, NN, NN, DIM, DIM);
  dmfma_k<double, float, 1, true><<<gd_k0, blk, 0, stream>>>(
      B1, w_down1, B2, b_down1, idx0, KP0, DIM, DIM, DIM, DIM, DIM);
  cvt64to32_k<<<cdiv(KP0 * DIM, 256), blk, 0, stream>>>(B2, Xd1f, KP0 * DIM);
  // 8) pool1 scores -> idx1, vals1, idx01
  score_keys_k<<<NN, dim3(64), 0, stream>>>(B2, p_w1, p_b1, KP0, keys);
  bitonic_k<<<1, dim3(1024), 65536, stream>>>(keys, KP1, idx1, vals1);
  compose_k<<<cdiv(KP1, 256), blk, 0, stream>>>(idx0, idx1, idx01, KP1);

  // ---- up path, bf16 MFMA ----
  // 9) Xb = relu(gather_idx01(A@Xp1s) @ w_bottom + b)
  hipMemsetAsync(Xs32, 0, (size_t)NN * DIM * 4, stream);
  scatter32_from64_k<<<cdiv(KP1 * DIM, 256), blk, 0, stream>>>(B2, idx1, vals1, idx01, Xs32, KP1);
  transpose_bf16_k<<<dim3(5, 64), blk, 0, stream>>>(Xs32, XbfT, NN, DIM);
  mfma_gemm_k<0, false, true><<<dim3(5, 32), blk, 0, stream>>>(
      Abf, XbfT, Tbf, nullptr, nullptr, nullptr, NN, DIM, NN, NN, NN, DIM, 0);
  mfma_gemm_k<1, true, false><<<dim3(5, cdiv(KP1, 128)), blk, 0, stream>>>(
      Tbf, wbT, Xc, b_bottom, nullptr, idx01, KP1, DIM, DIM, DIM, DIM, DIM, 0);
  // 10) Xu = relu(gather_idx0(A@scatter_idx01(Xb)) @ w_up0 + b) + Xd1
  hipMemsetAsync(Xs32, 0, (size_t)NN * DIM * 4, stream);
  scatter32_k<<<cdiv(KP1 * DIM, 256), blk, 0, stream>>>(Xc, idx01, Xs32, KP1);
  transpose_bf16_k<<<dim3(5, 64), blk, 0, stream>>>(Xs32, XbfT, NN, DIM);
  mfma_gemm_k<0, false, true><<<dim3(5, 32), blk, 0, stream>>>(
      Abf, XbfT, Tbf, nullptr, nullptr, nullptr, NN, DIM, NN, NN, NN, DIM, 0);
  mfma_gemm_k<2, true, false><<<dim3(5, cdiv(KP0, 128)), blk, 0, stream>>>(
      Tbf, wu0T, Xc, b_up0, Xd1f, idx0, KP0, DIM, DIM, DIM, DIM, DIM, DIM);
  // 11) Xu2 = relu(A@scatter_idx0(Xu) @ w_up1 + b) + Xd0  -> Xcat[:, :320]
  hipMemsetAsync(Xs32, 0, (size_t)NN * DIM * 4, stream);
  scatter32_k<<<cdiv(KP0 * DIM, 256), blk, 0, stream>>>(Xc, idx0, Xs32, KP0);
  transpose_bf16_k<<<dim3(5, 64), blk, 0, stream>>>(Xs32, XbfT, NN, DIM);
  mfma_gemm_k<0, false, true><<<dim3(5, 32), blk, 0, stream>>>(
      Abf, XbfT, Tbf, nullptr, nullptr, nullptr, NN, DIM, NN, NN, NN, DIM, 0);
  mfma_gemm_k<2, false, false><<<dim3(5, 32), blk, 0, stream>>>(
      Tbf, wu1T, Xcat, b_up1, Xd0f, nullptr, NN, DIM, DIM, DIM, DIM, 2 * DIM, DIM);
  copycols_k<<<cdiv(NN * DIM, 256), blk, 0, stream>>>(Xcat, out_x0);
  // 12) Xout = relu((A@Xcat) @ w_end + b_end)
  transpose_bf16_k<<<dim3(10, 64), blk, 0, stream>>>(Xcat, XbfT, NN, 2 * DIM);
  mfma_gemm_k<0, false, true><<<dim3(10, 32), blk, 0, stream>>>(
      Abf, XbfT, Tbf, nullptr, nullptr, nullptr, NN, 2 * DIM, NN, NN, NN, 2 * DIM, 0);
  mfma_gemm_k<1, false, false><<<dim3(5, 32), blk, 0, stream>>>(
      Tbf, weT, out_x, b_end, nullptr, nullptr, NN, DIM, 2 * DIM, 2 * DIM, 2 * DIM, DIM, 0);
  // 13) pool_out = Xp0 @ Xp0^T (both operands row-major-in-K), diag = 1
  mfma_gemm_k<0, false, false><<<dim3(cdiv(KP0, 64), cdiv(KP0, 128)), blk, 0, stream>>>(
      Pbf, Pbf, out_po, nullptr, nullptr, nullptr, KP0, KP0, DIM, DIM, DIM, KP0, 0);
  diag_k<<<cdiv(KP0, 256), blk, 0, stream>>>(out_po);
}

// Round 6
// 1408.634 us; speedup vs baseline: 1.4623x; 1.4623x over previous
//
#include <hip/hip_runtime.h>
#include <hip/hip_bf16.h>

// GraphUnet forward.
//  - Down path (feeds both top-k pools) in float64 via f64 MFMA
//    (v_mfma_f64_16x16x4): rank-exact ordering vs f64 numpy ref.
//  - top_k = bitonic sort on (f64 score bits, index), jax tie-break.
//  - Up path + pool_out: bf16 MFMA (16x16x32), fp32 accumulate (harness
//    compares in bf16; we sit at ~1.5 ulp of the output scale).
//  - A1 = A[idx][:,idx] never materialized: A1@Y = gather_idx(A @ scatter_idx(Y)).
//  - R5: R3 single-buffer K-loops (R4 dbuf spilled) + split-K=4 partials on the
//    big A-GEMMs for occupancy, deterministic fixed-order reduce kernels.
//  - R6 fix: step-12 split-K was launched with klen*gridZ=640 != K=4096
//    (contraction depth confused with N) -> Xout was A[:, :640]@Xcat[:640].
//    Now dim3(10,32,4) x klen=1024.

constexpr int NN  = 4096;
constexpr int DIM = 320;
constexpr int KP0 = 3686;
constexpr int KP1 = 2580;

typedef __attribute__((ext_vector_type(8))) short short8_t;
typedef __attribute__((ext_vector_type(4))) float floatx4;
typedef __attribute__((ext_vector_type(4))) double double4v;

// ---------------- f64 MFMA GEMM: C = A @ B (+bias, relu) ---------------------
// A: M x K (f32/f64) row-major.  B: K x N (f32/f64) row-major, staged as f64.
// C: M x N f64.  Tiles 64x32, BK=32; 4 waves (2x2), wave = 32m x 16n.
// Split-K via blockIdx.z: chunk z covers [z*klen, (z+1)*klen), partial written
// at Cg + z*M*ldc.  Launch with gridDim.z==1, klen==K for the direct form.
template<typename TA, typename TB, int EPI, bool AGATHER>
__global__ __launch_bounds__(256) void dmfma_k(
    const TA* __restrict__ Ag, const TB* __restrict__ Bg, double* __restrict__ Cg,
    const float* __restrict__ bias, const int* __restrict__ aidx,
    int M, int N, int klen, int lda, int ldb, int ldc)
{
  constexpr int BM = 64, BN = 32, BK = 32;
  constexpr int SA = (sizeof(TA) == 4) ? 36 : 34;   // row stride, elements
  constexpr int SB = 34;
  constexpr int EC  = 16 / (int)sizeof(TA);         // A elems per 16B chunk
  constexpr int CPR = BK / EC;                      // A chunks per row
  __shared__ TA     As[BM][SA];
  __shared__ double Bs[BK][SB];
  const int tid = threadIdx.x;
  const int wave = tid >> 6, lane = tid & 63;
  const int wm = wave >> 1, wn = wave & 1;
  const int m0 = blockIdx.y * BM, n0 = blockIdx.x * BN;
  const int ml = lane & 15, kl = lane >> 4;
  const int kof = blockIdx.z * klen;
  Cg += (size_t)blockIdx.z * M * ldc;

  double4v acc[2];
#pragma unroll
  for (int i = 0; i < 2; ++i)
#pragma unroll
    for (int r = 0; r < 4; ++r) acc[i][r] = 0.0;

  for (int k0 = kof; k0 < kof + klen; k0 += BK) {
#pragma unroll
    for (int i = 0; i < (BM * CPR) / 256; ++i) {
      int ch = tid + i * 256;
      int r = ch / CPR, cc = (ch % CPR) * EC;
      int row = m0 + r; if (row >= M) row = M - 1;
      int ar = AGATHER ? aidx[row] : row;
      *(uint4*)&As[r][cc] = *(const uint4*)&Ag[(size_t)ar * lda + k0 + cc];
    }
#pragma unroll
    for (int i = 0; i < 2; ++i) {
      int ch = tid + i * 256;                        // 512 chunks of 2 doubles
      int r = ch >> 4, cc = (ch & 15) * 2;
      const TB* src = &Bg[(size_t)(k0 + r) * ldb + n0 + cc];
      double2 v; v.x = (double)src[0]; v.y = (double)src[1];
      *(double2*)&Bs[r][cc] = v;
    }
    __syncthreads();
#pragma unroll
    for (int ks = 0; ks < BK; ks += 4) {
      double b  = Bs[ks + kl][wn * 16 + ml];
      double a0 = (double)As[wm * 32 + ml][ks + kl];
      double a1 = (double)As[wm * 32 + 16 + ml][ks + kl];
      acc[0] = __builtin_amdgcn_mfma_f64_16x16x4f64(a0, b, acc[0], 0, 0, 0);
      acc[1] = __builtin_amdgcn_mfma_f64_16x16x4f64(a1, b, acc[1], 0, 0, 0);
    }
    __syncthreads();
  }
  const int n = n0 + wn * 16 + ml;
#pragma unroll
  for (int mi = 0; mi < 2; ++mi)
#pragma unroll
    for (int r = 0; r < 4; ++r) {
      int m = m0 + wm * 32 + mi * 16 + kl * 4 + r;
      if (m >= M || n >= N) continue;
      double v = acc[mi][r];
      if (EPI == 1) { v += (double)bias[n]; v = v > 0.0 ? v : 0.0; }
      Cg[(size_t)m * ldc + n] = v;
    }
}

// fixed-order 4-way f64 partial reduce: dst = ((P0+P1)+P2)+P3
__global__ __launch_bounds__(256) void reduce64_k(
    const double* __restrict__ P, double* __restrict__ dst, int n, size_t stride)
{
  int g = (blockIdx.x * 256 + threadIdx.x) * 2;
  if (g >= n) return;
  double2 s = *(const double2*)(P + g);
#pragma unroll
  for (int p = 1; p < 4; ++p) {
    double2 v = *(const double2*)(P + p * stride + g);
    s.x += v.x; s.y += v.y;
  }
  *(double2*)(dst + g) = s;
}

// fixed-order f32 partial reduce -> bf16
__global__ __launch_bounds__(256) void reduceb_k(
    const float* __restrict__ P, __hip_bfloat16* __restrict__ dst,
    int n, int nparts, size_t stride)
{
  int g = (blockIdx.x * 256 + threadIdx.x) * 4;
  if (g >= n) return;
  float4 s = *(const float4*)(P + g);
  for (int p = 1; p < nparts; ++p) {
    float4 v = *(const float4*)(P + p * stride + g);
    s.x += v.x; s.y += v.y; s.z += v.z; s.w += v.w;
  }
  dst[g]     = __float2bfloat16(s.x);
  dst[g + 1] = __float2bfloat16(s.y);
  dst[g + 2] = __float2bfloat16(s.z);
  dst[g + 3] = __float2bfloat16(s.w);
}

// ---------------- bf16 MFMA GEMM: C = A @ Bt^T (+bias,relu)(+residual) -------
// A:  M x K row-major bf16 (rows optionally gathered via aidx).
// Bt: N x K row-major bf16.  C: M x N (f32 or bf16 per OUTBF).
// Tiles 128x64, BK=64, 4 waves (2x2), each wave 64x32.  Single-buffer (R3).
// Split-K via blockIdx.z (EPI must be 0 when gridDim.z > 1).
template<int EPI, bool AGATHER, bool OUTBF>
__global__ __launch_bounds__(256) void mfma_gemm_k(
    const __hip_bfloat16* __restrict__ Ag, const __hip_bfloat16* __restrict__ Btg,
    void* __restrict__ Cgv, const float* __restrict__ bias,
    const float* __restrict__ Rg, const int* __restrict__ aidx,
    int M, int N, int klen, int lda, int ldb, int ldc, int ldr)
{
  constexpr int BM = 128, BN = 64, BK = 64, BKP = 72;
  __shared__ ushort As[BM][BKP];
  __shared__ ushort Bs[BN][BKP];
  const int tid  = threadIdx.x;
  const int wave = tid >> 6, lane = tid & 63;
  const int wm = wave >> 1, wn = wave & 1;
  const int m0 = blockIdx.y * BM, n0 = blockIdx.x * BN;
  const int mlane = lane & 15;
  const int kq    = (lane >> 4) * 8;
  const int kof   = blockIdx.z * klen;
  const size_t zoff = (size_t)blockIdx.z * M * ldc;

  floatx4 acc[4][2];
#pragma unroll
  for (int i = 0; i < 4; ++i)
#pragma unroll
    for (int j = 0; j < 2; ++j) acc[i][j] = (floatx4)0.f;

  for (int k0 = kof; k0 < kof + klen; k0 += BK) {
#pragma unroll
    for (int i = 0; i < 4; ++i) {
      int ch = tid + i * 256;
      int r = ch >> 3, c8 = (ch & 7) * 8;
      int row = m0 + r; if (row >= M) row = M - 1;
      int ar = AGATHER ? aidx[row] : row;
      uint4 v = *(const uint4*)((const ushort*)Ag + (size_t)ar * lda + k0 + c8);
      *(uint4*)&As[r][c8] = v;
    }
#pragma unroll
    for (int i = 0; i < 2; ++i) {
      int ch = tid + i * 256;
      int r = ch >> 3, c8 = (ch & 7) * 8;
      int row = n0 + r; if (row >= N) row = N - 1;
      uint4 v = *(const uint4*)((const ushort*)Btg + (size_t)row * ldb + k0 + c8);
      *(uint4*)&Bs[r][c8] = v;
    }
    __syncthreads();
#pragma unroll
    for (int ks = 0; ks < BK; ks += 32) {
      short8_t aF[4], bF[2];
#pragma unroll
      for (int mi = 0; mi < 4; ++mi)
        aF[mi] = *(const short8_t*)&As[wm * 64 + mi * 16 + mlane][ks + kq];
#pragma unroll
      for (int ni = 0; ni < 2; ++ni)
        bF[ni] = *(const short8_t*)&Bs[wn * 32 + ni * 16 + mlane][ks + kq];
#pragma unroll
      for (int mi = 0; mi < 4; ++mi)
#pragma unroll
        for (int ni = 0; ni < 2; ++ni)
          acc[mi][ni] = __builtin_amdgcn_mfma_f32_16x16x32_bf16(
              aF[mi], bF[ni], acc[mi][ni], 0, 0, 0);
    }
    __syncthreads();
  }
  const int crow = (lane >> 4) * 4;
#pragma unroll
  for (int mi = 0; mi < 4; ++mi)
#pragma unroll
    for (int ni = 0; ni < 2; ++ni) {
      int n = n0 + wn * 32 + ni * 16 + mlane;
      if (n >= N) continue;
#pragma unroll
      for (int r = 0; r < 4; ++r) {
        int m = m0 + wm * 64 + mi * 16 + crow + r;
        if (m >= M) continue;
        float v = acc[mi][ni][r];
        if (EPI >= 1) { v += bias[n]; v = v > 0.f ? v : 0.f; }
        if (EPI == 2) v += Rg[(size_t)m * ldr + n];
        if (OUTBF) ((__hip_bfloat16*)Cgv)[zoff + (size_t)m * ldc + n] = __float2bfloat16(v);
        else       ((float*)Cgv)[zoff + (size_t)m * ldc + n] = v;
      }
    }
}

// ---------------- conversions ------------------------------------------------
__global__ __launch_bounds__(256) void cvtA_bf16_k(
    const float* __restrict__ src, __hip_bfloat16* __restrict__ dst, int n)
{
  int g = (blockIdx.x * 256 + threadIdx.x) * 4;
  if (g + 3 < n) {
    float4 v = *(const float4*)(src + g);
    dst[g]     = __float2bfloat16(v.x);
    dst[g + 1] = __float2bfloat16(v.y);
    dst[g + 2] = __float2bfloat16(v.z);
    dst[g + 3] = __float2bfloat16(v.w);
  } else {
    for (int i = g; i < n; ++i) dst[i] = __float2bfloat16(src[i]);
  }
}

// f32 src[R][C] -> bf16 dst[C][R], 64x64 LDS tiles, conflict-free (+1 pad)
__global__ __launch_bounds__(256) void transpose_bf16_k(
    const float* __restrict__ src, __hip_bfloat16* __restrict__ dst, int R, int C)
{
  __shared__ float s[64][65];
  int r0 = blockIdx.y * 64, c0 = blockIdx.x * 64;
  int tid = threadIdx.x;
  int c = tid & 63, rr = tid >> 6;
  for (int i = 0; i < 64; i += 4) {
    int r = rr + i;
    s[r][c] = (r0 + r < R && c0 + c < C) ? src[(size_t)(r0 + r) * C + c0 + c] : 0.f;
  }
  __syncthreads();
  int r2 = tid & 63, cc = tid >> 6;
  for (int i = 0; i < 64; i += 4) {
    int c2 = cc + i;
    if (c0 + c2 < C && r0 + r2 < R)
      dst[(size_t)(c0 + c2) * R + r0 + r2] = __float2bfloat16(s[r2][c2]);
  }
}

// ---------------- pooling scores -> sort keys --------------------------------
__global__ __launch_bounds__(64) void score_keys_k(
    const double* __restrict__ Xd, const float* __restrict__ pw,
    const float* __restrict__ pb, int n, ulonglong2* __restrict__ keys)
{
  int i = blockIdx.x;
  int lane = threadIdx.x;
  if (i >= n) {
    if (lane == 0) { ulonglong2 kv; kv.x = 0ull; kv.y = 0xFFFFFFFFull; keys[i] = kv; }
    return;
  }
  double p = 0.0;
#pragma unroll
  for (int c = 0; c < DIM; c += 64)
    p += Xd[(size_t)i * DIM + c + lane] * (double)pw[c + lane];
  for (int o = 32; o > 0; o >>= 1) p += __shfl_down(p, o, 64);
  if (lane == 0) {
    double z = (p + (double)pb[0]) / 100.0;
    double s;
    if (z >= 0.0) s = 1.0 / (1.0 + exp(-z));
    else { double e = exp(z); s = e / (1.0 + e); }   // stable branch (jax/scipy)
    ulonglong2 kv;
    kv.x = (unsigned long long)__double_as_longlong(s);
    kv.y = (unsigned long long)i;
    keys[i] = kv;
  }
}

__device__ __forceinline__ bool key_gt(const ulonglong2 a, const ulonglong2 b) {
  return (a.x > b.x) || (a.x == b.x && a.y < b.y);
}

__global__ __launch_bounds__(1024) void bitonic_k(
    const ulonglong2* __restrict__ keys, int k_keep,
    int* __restrict__ idx, double* __restrict__ vals)
{
  extern __shared__ ulonglong2 s[];
  int tid = threadIdx.x;
  for (int i = tid; i < NN; i += 1024) s[i] = keys[i];
  __syncthreads();
  for (int k = 2; k <= NN; k <<= 1) {
    for (int j = k >> 1; j > 0; j >>= 1) {
      for (int t = tid; t < NN; t += 1024) {
        int p = t ^ j;
        if (p > t) {
          ulonglong2 a = s[t], b = s[p];
          bool desc = ((t & k) == 0);
          bool sw = desc ? key_gt(b, a) : key_gt(a, b);
          if (sw) { s[t] = b; s[p] = a; }
        }
      }
      __syncthreads();
    }
  }
  for (int r = tid; r < k_keep; r += 1024) {
    idx[r]  = (int)s[r].y;
    vals[r] = __longlong_as_double((long long)s[r].x);
  }
}

// ---------------- small helpers ----------------------------------------------
__global__ void scatter64_k(const double* __restrict__ src, const int* __restrict__ sel,
                            const double* __restrict__ vals, const int* __restrict__ scat,
                            double* __restrict__ dst, __hip_bfloat16* __restrict__ comp,
                            int kcnt)
{
  int g = blockIdx.x * 256 + threadIdx.x;
  if (g >= kcnt * DIM) return;
  int r = g / DIM, c = g % DIM;
  double v = src[(size_t)sel[r] * DIM + c] * vals[r];
  dst[(size_t)scat[r] * DIM + c] = v;
  comp[g] = __float2bfloat16((float)v);
}

__global__ void scatter32_from64_k(const double* __restrict__ src, const int* __restrict__ sel,
                                   const double* __restrict__ vals, const int* __restrict__ scat,
                                   float* __restrict__ dst, int kcnt)
{
  int g = blockIdx.x * 256 + threadIdx.x;
  if (g >= kcnt * DIM) return;
  int r = g / DIM, c = g % DIM;
  dst[(size_t)scat[r] * DIM + c] = (float)(src[(size_t)sel[r] * DIM + c] * vals[r]);
}

__global__ void scatter32_k(const float* __restrict__ src, const int* __restrict__ scat,
                            float* __restrict__ dst, int kcnt)
{
  int g = blockIdx.x * 256 + threadIdx.x;
  if (g >= kcnt * DIM) return;
  int r = g / DIM, c = g % DIM;
  dst[(size_t)scat[r] * DIM + c] = src[g];
}

__global__ void cvt64to32_k(const double* __restrict__ src, float* __restrict__ dst, int n)
{
  int g = blockIdx.x * 256 + threadIdx.x;
  if (g < n) dst[g] = (float)src[g];
}

__global__ void compose_k(const int* __restrict__ idx0, const int* __restrict__ idx1,
                          int* __restrict__ idx01, int n)
{
  int g = blockIdx.x * 256 + threadIdx.x;
  if (g < n) idx01[g] = idx0[idx1[g]];
}

__global__ void copycols_k(float* __restrict__ xcat, const float* __restrict__ x0)
{
  int g = blockIdx.x * 256 + threadIdx.x;
  if (g >= NN * DIM) return;
  int r = g / DIM, c = g % DIM;
  xcat[(size_t)r * (2 * DIM) + DIM + c] = x0[g];
}

__global__ void diag_k(float* __restrict__ po)
{
  int g = blockIdx.x * 256 + threadIdx.x;
  if (g < KP0) po[(size_t)g * KP0 + g] = 1.0f;
}

// ---------------- launch ------------------------------------------------------
extern "C" void kernel_launch(void* const* d_in, const int* in_sizes, int n_in,
                              void* d_out, int out_size, void* d_ws, size_t ws_size,
                              hipStream_t stream) {
  const float* A        = (const float*)d_in[0];
  const float* X        = (const float*)d_in[1];
  const float* w_start  = (const float*)d_in[2];
  const float* b_start  = (const float*)d_in[3];
  const float* w_down0  = (const float*)d_in[4];
  const float* b_down0  = (const float*)d_in[5];
  const float* w_down1  = (const float*)d_in[6];
  const float* b_down1  = (const float*)d_in[7];
  const float* p_w0     = (const float*)d_in[8];
  const float* p_b0     = (const float*)d_in[9];
  const float* p_w1     = (const float*)d_in[10];
  const float* p_b1     = (const float*)d_in[11];
  const float* w_bottom = (const float*)d_in[12];
  const float* b_bottom = (const float*)d_in[13];
  const float* w_up0    = (const float*)d_in[14];
  const float* b_up0    = (const float*)d_in[15];
  const float* w_up1    = (const float*)d_in[16];
  const float* b_up1    = (const float*)d_in[17];
  const float* w_end    = (const float*)d_in[18];
  const float* b_end    = (const float*)d_in[19];

  float* out_x  = (float*)d_out;             // Xout   [4096,320]
  float* out_x0 = out_x + NN * DIM;          // X0     [4096,320]
  float* out_po = out_x0 + NN * DIM;         // pool   [3686,3686]

  char*  wsb = (char*)d_ws;
  size_t off = 0;
  auto alloc = [&](size_t bytes) -> void* {
    void* p = wsb + off; off = (off + bytes + 255) & ~(size_t)255; return p;
  };
  double* B1   = (double*)alloc((size_t)NN * DIM * 8);
  double* B2   = (double*)alloc((size_t)NN * DIM * 8);
  double* B3   = (double*)alloc((size_t)NN * DIM * 8);
  float*  Xd0f = (float*) alloc((size_t)NN * DIM * 4);
  float*  Xd1f = (float*) alloc((size_t)KP0 * DIM * 4);
  float*  Xs32 = (float*) alloc((size_t)NN * DIM * 4);
  float*  Xc   = (float*) alloc((size_t)KP0 * DIM * 4);
  float*  Xcat = (float*) alloc((size_t)NN * 2 * DIM * 4);
  // split-K partial area: 4 x (4096x320) f64 == 4 x (4096x640) f32 == 41.94 MB
  char*   Part = (char*)  alloc((size_t)4 * NN * DIM * 8);
  double* Pd   = (double*)Part;
  float*  Pf   = (float*) Part;
  __hip_bfloat16* Abf  = (__hip_bfloat16*)alloc((size_t)NN * NN * 2);
  __hip_bfloat16* XbfT = (__hip_bfloat16*)alloc((size_t)2 * DIM * NN * 2);
  __hip_bfloat16* Tbf  = (__hip_bfloat16*)alloc((size_t)NN * 2 * DIM * 2);
  __hip_bfloat16* Pbf  = (__hip_bfloat16*)alloc((size_t)KP0 * DIM * 2);
  __hip_bfloat16* wbT  = (__hip_bfloat16*)alloc((size_t)DIM * DIM * 2);
  __hip_bfloat16* wu0T = (__hip_bfloat16*)alloc((size_t)DIM * DIM * 2);
  __hip_bfloat16* wu1T = (__hip_bfloat16*)alloc((size_t)DIM * DIM * 2);
  __hip_bfloat16* weT  = (__hip_bfloat16*)alloc((size_t)DIM * 2 * DIM * 2);
  ulonglong2* keys = (ulonglong2*)alloc((size_t)NN * 16);
  int*    idx0  = (int*)   alloc(4096 * 4);
  double* vals0 = (double*)alloc(4096 * 8);
  int*    idx1  = (int*)   alloc(4096 * 4);
  double* vals1 = (double*)alloc(4096 * 8);
  int*    idx01 = (int*)   alloc(4096 * 4);

  const dim3 blk(256);
  auto cdiv = [](int a, int b) { return (a + b - 1) / b; };
  const dim3 gd_split(DIM / 32, NN / 64, 4);   // f64 big A-GEMM: 2560 blocks
  const dim3 gd_sm   (DIM / 32, NN / 64, 1);   // f64 small-K GEMM
  const dim3 gd_smk0 (DIM / 32, cdiv(KP0, 64), 1);
  const size_t strd64 = (size_t)NN * DIM;

  // One-time conversions (independent of everything downstream)
  cvtA_bf16_k<<<cdiv(NN * NN / 4, 256), blk, 0, stream>>>(A, Abf, NN * NN);
  transpose_bf16_k<<<dim3(5, 5),  blk, 0, stream>>>(w_bottom, wbT,  DIM, DIM);
  transpose_bf16_k<<<dim3(5, 5),  blk, 0, stream>>>(w_up0,    wu0T, DIM, DIM);
  transpose_bf16_k<<<dim3(5, 5),  blk, 0, stream>>>(w_up1,    wu1T, DIM, DIM);
  transpose_bf16_k<<<dim3(5, 10), blk, 0, stream>>>(w_end,    weT,  2 * DIM, DIM);

  // ---- down path, f64 MFMA (big GEMMs split-K=4, klen=1024) ----
  // 1) T = A @ X
  dmfma_k<float, float, 0, false><<<gd_split, blk, 0, stream>>>(
      A, X, Pd, nullptr, nullptr, NN, DIM, 1024, NN, DIM, DIM);
  reduce64_k<<<cdiv(NN * DIM / 2, 256), blk, 0, stream>>>(Pd, B1, NN * DIM, strd64);
  // 2) X0 = relu(T @ w_start + b)
  dmfma_k<double, float, 1, false><<<gd_sm, blk, 0, stream>>>(
      B1, w_start, B2, b_start, nullptr, NN, DIM, DIM, DIM, DIM, DIM);
  cvt64to32_k<<<cdiv(NN * DIM, 256), blk, 0, stream>>>(B2, out_x0, NN * DIM);
  // 3) T = A @ X0
  dmfma_k<float, double, 0, false><<<gd_split, blk, 0, stream>>>(
      A, B2, Pd, nullptr, nullptr, NN, DIM, 1024, NN, DIM, DIM);
  reduce64_k<<<cdiv(NN * DIM / 2, 256), blk, 0, stream>>>(Pd, B1, NN * DIM, strd64);
  // 4) Xd0 = relu(T @ w_down0 + b)
  dmfma_k<double, float, 1, false><<<gd_sm, blk, 0, stream>>>(
      B1, w_down0, B3, b_down0, nullptr, NN, DIM, DIM, DIM, DIM, DIM);
  cvt64to32_k<<<cdiv(NN * DIM, 256), blk, 0, stream>>>(B3, Xd0f, NN * DIM);
  // 5) pool0 scores -> sort -> idx0, vals0
  score_keys_k<<<NN, dim3(64), 0, stream>>>(B3, p_w0, p_b0, NN, keys);
  bitonic_k<<<1, dim3(1024), 65536, stream>>>(keys, KP0, idx0, vals0);
  // 6) Xp0: scattered f64 + compact bf16 (for pool_out)
  hipMemsetAsync(B2, 0, (size_t)NN * DIM * 8, stream);
  scatter64_k<<<cdiv(KP0 * DIM, 256), blk, 0, stream>>>(B3, idx0, vals0, idx0, B2, Pbf, KP0);
  // 7) T = A @ Xp0s ; Xd1 = relu(gather_idx0(T) @ w_down1 + b)
  dmfma_k<float, double, 0, false><<<gd_split, blk, 0, stream>>>(
      A, B2, Pd, nullptr, nullptr, NN, DIM, 1024, NN, DIM, DIM);
  reduce64_k<<<cdiv(NN * DIM / 2, 256), blk, 0, stream>>>(Pd, B1, NN * DIM, strd64);
  dmfma_k<double, float, 1, true><<<gd_smk0, blk, 0, stream>>>(
      B1, w_down1, B2, b_down1, idx0, KP0, DIM, DIM, DIM, DIM, DIM);
  cvt64to32_k<<<cdiv(KP0 * DIM, 256), blk, 0, stream>>>(B2, Xd1f, KP0 * DIM);
  // 8) pool1 scores -> idx1, vals1, idx01
  score_keys_k<<<NN, dim3(64), 0, stream>>>(B2, p_w1, p_b1, KP0, keys);
  bitonic_k<<<1, dim3(1024), 65536, stream>>>(keys, KP1, idx1, vals1);
  compose_k<<<cdiv(KP1, 256), blk, 0, stream>>>(idx0, idx1, idx01, KP1);

  // ---- up path, bf16 MFMA (big A-GEMMs split-K=4, klen=1024) ----
  // 9) Xb = relu(gather_idx01(A@Xp1s) @ w_bottom + b)
  hipMemsetAsync(Xs32, 0, (size_t)NN * DIM * 4, stream);
  scatter32_from64_k<<<cdiv(KP1 * DIM, 256), blk, 0, stream>>>(B2, idx1, vals1, idx01, Xs32, KP1);
  transpose_bf16_k<<<dim3(5, 64), blk, 0, stream>>>(Xs32, XbfT, NN, DIM);
  mfma_gemm_k<0, false, false><<<dim3(5, 32, 4), blk, 0, stream>>>(
      Abf, XbfT, Pf, nullptr, nullptr, nullptr, NN, DIM, 1024, NN, NN, DIM, 0);
  reduceb_k<<<cdiv(NN * DIM / 4, 256), blk, 0, stream>>>(Pf, Tbf, NN * DIM, 4, strd64);
  mfma_gemm_k<1, true, false><<<dim3(5, cdiv(KP1, 128), 1), blk, 0, stream>>>(
      Tbf, wbT, Xc, b_bottom, nullptr, idx01, KP1, DIM, DIM, DIM, DIM, DIM, 0);
  // 10) Xu = relu(gather_idx0(A@scatter_idx01(Xb)) @ w_up0 + b) + Xd1
  hipMemsetAsync(Xs32, 0, (size_t)NN * DIM * 4, stream);
  scatter32_k<<<cdiv(KP1 * DIM, 256), blk, 0, stream>>>(Xc, idx01, Xs32, KP1);
  transpose_bf16_k<<<dim3(5, 64), blk, 0, stream>>>(Xs32, XbfT, NN, DIM);
  mfma_gemm_k<0, false, false><<<dim3(5, 32, 4), blk, 0, stream>>>(
      Abf, XbfT, Pf, nullptr, nullptr, nullptr, NN, DIM, 1024, NN, NN, DIM, 0);
  reduceb_k<<<cdiv(NN * DIM / 4, 256), blk, 0, stream>>>(Pf, Tbf, NN * DIM, 4, strd64);
  mfma_gemm_k<2, true, false><<<dim3(5, cdiv(KP0, 128), 1), blk, 0, stream>>>(
      Tbf, wu0T, Xc, b_up0, Xd1f, idx0, KP0, DIM, DIM, DIM, DIM, DIM, DIM);
  // 11) Xu2 = relu(A@scatter_idx0(Xu) @ w_up1 + b) + Xd0  -> Xcat[:, :320]
  hipMemsetAsync(Xs32, 0, (size_t)NN * DIM * 4, stream);
  scatter32_k<<<cdiv(KP0 * DIM, 256), blk, 0, stream>>>(Xc, idx0, Xs32, KP0);
  transpose_bf16_k<<<dim3(5, 64), blk, 0, stream>>>(Xs32, XbfT, NN, DIM);
  mfma_gemm_k<0, false, false><<<dim3(5, 32, 4), blk, 0, stream>>>(
      Abf, XbfT, Pf, nullptr, nullptr, nullptr, NN, DIM, 1024, NN, NN, DIM, 0);
  reduceb_k<<<cdiv(NN * DIM / 4, 256), blk, 0, stream>>>(Pf, Tbf, NN * DIM, 4, strd64);
  mfma_gemm_k<2, false, false><<<dim3(5, 32, 1), blk, 0, stream>>>(
      Tbf, wu1T, Xcat, b_up1, Xd0f, nullptr, NN, DIM, DIM, DIM, DIM, 2 * DIM, DIM);
  copycols_k<<<cdiv(NN * DIM, 256), blk, 0, stream>>>(Xcat, out_x0);
  // 12) Xout = relu((A@Xcat) @ w_end + b_end)
  //     A@Xcat: M=4096, N=640, K=4096 -> split-K=4, klen=1024
  //     (R5 bug: used klen*gridZ=640, conflating contraction depth with N)
  transpose_bf16_k<<<dim3(10, 64), blk, 0, stream>>>(Xcat, XbfT, NN, 2 * DIM);
  mfma_gemm_k<0, false, false><<<dim3(10, 32, 4), blk, 0, stream>>>(
      Abf, XbfT, Pf, nullptr, nullptr, nullptr, NN, 2 * DIM, 1024, NN, NN, 2 * DIM, 0);
  reduceb_k<<<cdiv(NN * 2 * DIM / 4, 256), blk, 0, stream>>>(
      Pf, Tbf, NN * 2 * DIM, 4, (size_t)NN * 2 * DIM);
  mfma_gemm_k<1, false, false><<<dim3(5, 32, 1), blk, 0, stream>>>(
      Tbf, weT, out_x, b_end, nullptr, nullptr, NN, DIM, 2 * DIM, 2 * DIM, 2 * DIM, DIM, 0);
  // 13) pool_out = Xp0 @ Xp0^T (both operands row-major-in-K), diag = 1
  mfma_gemm_k<0, false, false><<<dim3(cdiv(KP0, 64), cdiv(KP0, 128), 1), blk, 0, stream>>>(
      Pbf, Pbf, out_po, nullptr, nullptr, nullptr, KP0, KP0, DIM, DIM, DIM, KP0, 0);
  diag_k<<<cdiv(KP0, 256), blk, 0, stream>>>(out_po);
}